// Round 2
// baseline (170.616 us; speedup 1.0000x reference)
//
#include <hip/hip_runtime.h>

#define NN 512   // N
#define DD 16    // D (16 floats = 4 float4)

typedef __attribute__((ext_vector_type(4))) float f32x4;

// ---------------- Kernel A: per-row neighbor compaction -> workspace ----------
// One block per (b,i) row; 512 threads. All ballot/barrier work lives here.
// Writes the compacted neighbor-index table nbw[row][512] (8 MiB, L2-resident).
__global__ __launch_bounds__(512) void compact_kernel(
    const int* __restrict__ adj,   // [B][N][N] int32
    int*       __restrict__ nbw)   // [B*N][N] compacted indices
{
    __shared__ int snb[NN];
    __shared__ int wtot[8];

    const int row  = blockIdx.x;
    const int t    = threadIdx.x;
    const int lane = t & 63;
    const int wv   = t >> 6;

    // stable ascending compaction of valid columns: sort(where(valid, cols, n))[:n-1]
    const int  a     = adj[(size_t)row * NN + t];
    const bool valid = (a != -1);
    const unsigned long long m = __ballot(valid);
    const int  rank  = __popcll(m & ((1ULL << lane) - 1ULL));
    snb[t] = NN - 1;                 // JAX out-of-bounds gather clamps n -> n-1
    if (lane == 0) wtot[wv] = __popcll(m);
    __syncthreads();

    int base = 0;
    #pragma unroll
    for (int w = 0; w < 8; ++w)
        base += (w < wv) ? wtot[w] : 0;
    if (valid) {
        const int pos = base + rank;
        if (pos < NN) snb[pos] = t;
    }
    __syncthreads();

    nbw[(size_t)row * NN + t] = snb[t];   // coalesced
}

// ---------------- Kernel B: pure streaming expand ----------------------------
// Structurally identical to a fill kernel: no LDS, no barriers, low VGPR,
// 256-thread blocks, coalesced float4 NT stores. Per store: 3 small gathers
// (nbw: L2 8 MiB; coef: streamed 8 MiB; msg: L2-resident 256 KiB).
__global__ __launch_bounds__(256) void expand_kernel(
    const int*    __restrict__ nbw,    // [B*N][N]
    const float*  __restrict__ coef,   // [B][N][N]
    const float4* __restrict__ msg4,   // [B][N][4]
    float4*       __restrict__ out4)   // [B][N][N*4]
{
    const unsigned tid = blockIdx.x * 256u + threadIdx.x;
    // total float4s = 4096 rows * 2048 = 8,388,608 ; 4096 blocks * 256 thr * 8 iters
    #pragma unroll
    for (int k = 0; k < 8; ++k) {
        const unsigned g   = tid + (unsigned)k * (4096u * 256u);
        const unsigned row = g >> 11;         // 2048 float4 per output row
        const unsigned r   = g & 2047u;
        const unsigned j   = r >> 2;          // output column (neighbor slot)
        const unsigned q   = r & 3u;          // which float4 of the D=16 message
        const unsigned b   = row >> 9;
        const unsigned i   = row & 511u;
        const unsigned s   = (j == 0) ? i : (unsigned)nbw[row * 512u + (j - 1)];
        const float    c   = coef[row * 512u + j];
        const float4   v   = msg4[(b << 11) + (s << 2) + q];
        f32x4 o = { c * v.x, c * v.y, c * v.z, c * v.w };
        __builtin_nontemporal_store(o, (f32x4*)&out4[g]);
    }
}

// ---------------- Fallback: previous monolithic kernel (ws too small) --------
__global__ __launch_bounds__(512) void graph_layer_kernel(
    const int*    __restrict__ adj,
    const float*  __restrict__ coef,
    const float4* __restrict__ msg4,
    float4*       __restrict__ out4)
{
    __shared__ float scoef[NN];
    __shared__ int   snb[NN];
    __shared__ int   wtot[8];

    const int row  = blockIdx.x;
    const int b    = row >> 9;
    const int i    = row & (NN - 1);
    const int t    = threadIdx.x;
    const int lane = t & 63;
    const int wv   = t >> 6;

    scoef[t] = coef[(size_t)row * NN + t];

    const int  a     = adj[(size_t)row * NN + t];
    const bool valid = (a != -1);
    const unsigned long long m = __ballot(valid);
    const int  rank  = __popcll(m & ((1ULL << lane) - 1ULL));
    snb[t] = NN - 1;
    if (lane == 0) wtot[wv] = __popcll(m);
    __syncthreads();

    int base = 0;
    #pragma unroll
    for (int w = 0; w < 8; ++w)
        base += (w < wv) ? wtot[w] : 0;
    if (valid) {
        const int pos = base + rank;
        if (pos < NN) snb[pos] = t;
    }
    __syncthreads();

    const float4* mb   = msg4 + (size_t)b * (NN * 4);
    float4*       orow = out4 + (size_t)row * (NN * 4);
    #pragma unroll
    for (int k = 0; k < 4; ++k) {
        const int g = t + k * 512;
        const int j = g >> 2;
        const int q = g & 3;
        const int s = (j == 0) ? i : snb[j - 1];
        const float c = scoef[j];
        const float4 v = mb[s * 4 + q];
        f32x4 o = { c * v.x, c * v.y, c * v.z, c * v.w };
        __builtin_nontemporal_store(o, (f32x4*)&orow[g]);
    }
}

extern "C" void kernel_launch(void* const* d_in, const int* in_sizes, int n_in,
                              void* d_out, int out_size, void* d_ws, size_t ws_size,
                              hipStream_t stream) {
    const int*    adj  = (const int*)d_in[0];     // adj_matrix (int32)
    const float*  coef = (const float*)d_in[1];   // adj_coef
    const float4* msg4 = (const float4*)d_in[2];  // neighbour_messages
    float4*       out4 = (float4*)d_out;

    const int B = 8;
    const size_t ws_needed = (size_t)B * NN * NN * sizeof(int);  // 8 MiB

    if (ws_size >= ws_needed && d_ws != nullptr) {
        int* nbw = (int*)d_ws;
        compact_kernel<<<B * NN, 512, 0, stream>>>(adj, nbw);
        expand_kernel<<<4096, 256, 0, stream>>>(nbw, coef, msg4, out4);
    } else {
        graph_layer_kernel<<<B * NN, 512, 0, stream>>>(adj, coef, msg4, out4);
    }
}

// Round 3
// 165.116 us; speedup vs baseline: 1.0333x; 1.0333x over previous
//
#include <hip/hip_runtime.h>

#define NN  512   // N
#define RPB 4     // rows per block (amortize preamble over 4x output bytes)

typedef __attribute__((ext_vector_type(4))) float f32x4;

// Single launch, 1024 blocks x 512 threads. Each block owns 4 consecutive
// output rows (never crosses a batch boundary: 512 % 4 == 0).
// Preamble (adj load + ballot compaction + 2 barriers) is paid once per
// 128 KiB of output instead of once per 32 KiB.
// coef/msg are read directly from global (msg is 32 KiB/batch, L1-resident;
// coef is streamed exactly once) — no LDS round-trips except the snb table,
// which genuinely needs the cross-thread scatter.
__global__ __launch_bounds__(512) void graph_layer_kernel(
    const int*    __restrict__ adj,    // [B][N][N] int32
    const float*  __restrict__ coef,   // [B][N][N] fp32
    const float4* __restrict__ msg4,   // [B][N][4] (= [B][N][16] fp32)
    float4*       __restrict__ out4)   // [B][N][N*4]
{
    __shared__ int snb[RPB][NN];       // 8 KiB: compacted neighbor indices
    __shared__ int wtot[RPB][8];       // per-wave valid counts

    const int row0 = blockIdx.x * RPB; // first of 4 rows
    const int t    = threadIdx.x;
    const int lane = t & 63;
    const int wv   = t >> 6;
    const int b    = row0 >> 9;        // batch (same for all 4 rows)

    // --- preamble: compaction for 4 rows ---
    // sort(where(valid, cols, n))[:n-1]; fill = n clamped to n-1 (JAX gather clamp)
    unsigned long long m[RPB];
    int  rank [RPB];
    bool valid[RPB];
    #pragma unroll
    for (int r = 0; r < RPB; ++r) {
        const int a = adj[(size_t)(row0 + r) * NN + t];
        valid[r] = (a != -1);
        m[r]     = __ballot(valid[r]);
        rank[r]  = __popcll(m[r] & ((1ULL << lane) - 1ULL));
        snb[r][t] = NN - 1;
        if (lane == 0) wtot[r][wv] = __popcll(m[r]);
    }
    __syncthreads();

    #pragma unroll
    for (int r = 0; r < RPB; ++r) {
        int base = 0;
        #pragma unroll
        for (int w = 0; w < 8; ++w)
            base += (w < wv) ? wtot[r][w] : 0;
        if (valid[r]) {
            const int pos = base + rank[r];
            if (pos < NN) snb[r][pos] = t;
        }
    }
    __syncthreads();

    // --- stores: 4 rows x 4 iterations x 512 float4 (fully coalesced) ---
    const float4* mb = msg4 + ((size_t)b << 11);   // this batch's messages
    #pragma unroll 1                               // keep VGPR pressure low
    for (int r = 0; r < RPB; ++r) {
        const int    row  = row0 + r;
        const int    i    = row & (NN - 1);
        const float* crow = coef + (size_t)row * NN;
        float4*      orow = out4 + (size_t)row * (NN * 4);
        const int    ph   = row & 3;               // free phase rotation
        #pragma unroll
        for (int kk = 0; kk < 4; ++kk) {
            const int k = (kk + ph) & 3;
            const int g = t + k * 512;             // float4 index in the row
            const int j = g >> 2;                  // output column
            const int q = g & 3;                   // float4 within D=16 msg
            const int s = (j == 0) ? i : snb[r][j - 1];
            const float  c = crow[j];
            const float4 v = mb[(s << 2) + q];
            f32x4 o = { c * v.x, c * v.y, c * v.z, c * v.w };
            *(f32x4*)&orow[g] = o;
        }
    }
}

extern "C" void kernel_launch(void* const* d_in, const int* in_sizes, int n_in,
                              void* d_out, int out_size, void* d_ws, size_t ws_size,
                              hipStream_t stream) {
    const int*    adj  = (const int*)d_in[0];     // adj_matrix (int32)
    const float*  coef = (const float*)d_in[1];   // adj_coef
    const float4* msg4 = (const float4*)d_in[2];  // neighbour_messages
    float4*       out4 = (float4*)d_out;          // fp32 output

    const int B = 8;
    graph_layer_kernel<<<(B * NN) / RPB, 512, 0, stream>>>(adj, coef, msg4, out4);
}

// Round 4
// 158.540 us; speedup vs baseline: 1.0762x; 1.0415x over previous
//
#include <hip/hip_runtime.h>

#define NN 512   // N
#define DD 16    // D (16 floats = 4 float4)

// R4 = exact reversion to R0, the best-measured kernel (156.1 µs).
// Experiment matrix R0-R3: LDS-staged / direct-read / split-streaming /
// row-fused all within 156-171 µs, every delta vs R0 explained by ADDED
// overhead (extra launch, ws round-trip, VGPR/serialization), never by a
// removed bottleneck -> kernel phase is at its memory floor (~30 µs vs
// 23 µs mandatory 144 MiB at achieved 6.5 TB/s); the rest of the timed
// region is fixed harness work (512 MiB poison fill ~81 µs + restores).
//
// One block per (b, i) output row. Block = 512 threads (8 waves).
// LDS: messages for batch b (32 KiB) + coef row (2 KiB) + neighbor idx (2 KiB).
__global__ __launch_bounds__(512) void graph_layer_kernel(
    const int*    __restrict__ adj,    // [B][N][N] int32
    const float*  __restrict__ coef,   // [B][N][N] fp32
    const float4* __restrict__ msg4,   // [B][N][4] (= [B][N][16] fp32)
    float4*       __restrict__ out4)   // [B][N][N*4] (= [B][N][N*16] fp32)
{
    __shared__ float4 smsg[NN * 4];    // 32 KiB: messages of this batch
    __shared__ float  scoef[NN];       // 2 KiB
    __shared__ int    snb[NN];         // compacted valid-column indices
    __shared__ int    wtot[8];         // per-wave valid counts

    const int row  = blockIdx.x;       // b*N + i
    const int b    = row >> 9;
    const int i    = row & (NN - 1);
    const int t    = threadIdx.x;
    const int lane = t & 63;
    const int wv   = t >> 6;

    // --- stage coef row (coalesced) ---
    scoef[t] = coef[(size_t)row * NN + t];

    // --- stage this batch's messages (coalesced float4, 32 KiB) ---
    {
        const float4* src = msg4 + (size_t)b * (NN * 4);
        #pragma unroll
        for (int k = 0; k < 4; ++k)
            smsg[t + k * 512] = src[t + k * 512];
    }

    // --- general neighbor compaction: sort(where(valid, cols, n))[:n-1] ---
    // stable ascending compaction of valid columns; fill = n clamped to n-1
    const int  a     = adj[(size_t)row * NN + t];
    const bool valid = (a != -1);
    const unsigned long long m = __ballot(valid);
    const int  rank  = __popcll(m & ((1ULL << lane) - 1ULL));
    snb[t] = NN - 1;                   // JAX out-of-bounds gather clamps n -> n-1
    if (lane == 0) wtot[wv] = __popcll(m);
    __syncthreads();

    int base = 0;
    #pragma unroll
    for (int w = 0; w < 8; ++w)
        base += (w < wv) ? wtot[w] : 0;
    if (valid) {
        const int pos = base + rank;
        if (pos < NN) snb[pos] = t;
    }
    __syncthreads();

    // --- produce the output row: 8192 floats = 2048 float4, coalesced ---
    float4* orow = out4 + (size_t)row * (NN * 4);
    #pragma unroll
    for (int k = 0; k < 4; ++k) {
        const int g = t + k * 512;     // float4 index within the row
        const int j = g >> 2;          // output column (which neighbor slot)
        const int q = g & 3;           // which float4 of the D=16 message
        const int s = (j == 0) ? i : snb[j - 1];
        const float c = scoef[j];
        const float4 v = smsg[s * 4 + q];
        float4 o;
        o.x = c * v.x; o.y = c * v.y; o.z = c * v.z; o.w = c * v.w;
        orow[g] = o;
    }
}

extern "C" void kernel_launch(void* const* d_in, const int* in_sizes, int n_in,
                              void* d_out, int out_size, void* d_ws, size_t ws_size,
                              hipStream_t stream) {
    const int*    adj  = (const int*)d_in[0];     // adj_matrix (int32)
    const float*  coef = (const float*)d_in[1];   // adj_coef
    const float4* msg4 = (const float4*)d_in[2];  // neighbour_messages
    float4*       out4 = (float4*)d_out;          // fp32 output

    const int B = 8;
    graph_layer_kernel<<<B * NN, 512, 0, stream>>>(adj, coef, msg4, out4);
}